// Round 10
// baseline (243.002 us; speedup 1.0000x reference)
//
#include <hip/hip_runtime.h>
#include <hip/hip_bf16.h>
#include <math.h>

typedef long long i64;

__device__ __forceinline__ float bfu(unsigned short u) {
    union { unsigned int i; float f; } v; v.i = ((unsigned)u) << 16; return v.f;
}
__device__ __forceinline__ unsigned short f2b(float f) {
    __hip_bfloat16 h = __float2bfloat16(f);
    return *reinterpret_cast<unsigned short*>(&h);
}

// ================= CSR build: 2-phase radix partition by dst =================
#define NPB_SHIFT 9
#define NPB 512
#define LCAP 16384
#define P1C 4096

__global__ void k_zeroB(int* __restrict__ bcnt, int B) {
    int t = threadIdx.x;
    if (t <= B) bcnt[t] = 0;
}

__global__ __launch_bounds__(256) void k_p1count(
    const int* __restrict__ dst, int E, int B, int* __restrict__ bcnt) {
    __shared__ int lb[256];
    int t = threadIdx.x;
    lb[t] = 0; __syncthreads();
    int cpb = (E + gridDim.x - 1) / gridDim.x;
    int s0 = blockIdx.x * cpb, s1 = min(E, s0 + cpb);
    for (int i = s0 + t; i < s1; i += 256)
        atomicAdd(&lb[dst[i] >> NPB_SHIFT], 1);
    __syncthreads();
    if (t < B && lb[t]) atomicAdd(&bcnt[t], lb[t]);
}

__global__ void k_scanB(const int* __restrict__ bcnt, int B, int E,
                        int* __restrict__ bstart, int* __restrict__ cursor) {
    __shared__ int s[256];
    int t = threadIdx.x;
    int v = (t < B) ? bcnt[t] : 0;
    s[t] = v; __syncthreads();
    for (int off = 1; off < 256; off <<= 1) {
        int u = (t >= off) ? s[t - off] : 0;
        __syncthreads();
        s[t] += u;
        __syncthreads();
    }
    int excl = s[t] - v;
    if (t < B) { bstart[t] = excl; cursor[t] = excl; }
    if (t == 0) bstart[B] = E;
}

__global__ __launch_bounds__(256) void k_p1place(
    const int* __restrict__ src, const int* __restrict__ dst, int E, int B,
    int* __restrict__ cursor, uint2* __restrict__ pairs) {
    __shared__ int ls_s[P1C];
    __shared__ int ls_d[P1C];
    __shared__ int lb[256];
    __shared__ int lbase[256];
    int t = threadIdx.x;
    int s0 = blockIdx.x * P1C, s1 = min(E, s0 + P1C), n = s1 - s0;
    lb[t] = 0; __syncthreads();
    for (int i = t; i < n; i += 256) {
        int d = dst[s0 + i];
        ls_d[i] = d;
        ls_s[i] = src[s0 + i];
        atomicAdd(&lb[d >> NPB_SHIFT], 1);
    }
    __syncthreads();
    if (t < B && lb[t]) lbase[t] = atomicAdd(&cursor[t], lb[t]);
    __syncthreads();
    lb[t] = 0; __syncthreads();
    for (int i = t; i < n; i += 256) {
        int d = ls_d[i];
        int bkt = d >> NPB_SHIFT;
        int slot = atomicAdd(&lb[bkt], 1);
        pairs[lbase[bkt] + slot] = make_uint2((unsigned)ls_s[i], (unsigned)d);
    }
}

__global__ __launch_bounds__(512) void k_p2(
    const uint2* __restrict__ pairs, const int* __restrict__ bstart,
    int* __restrict__ rowptr, float* __restrict__ dinv,
    int* __restrict__ col, int N, int E) {
    __shared__ int lcnt[NPB];
    __shared__ int lscan[NPB];
    __shared__ int lcol[LCAP];
    int b = blockIdx.x, t = threadIdx.x;
    int lo = b << NPB_SHIFT, hi = min(N, lo + NPB), nn = hi - lo;
    int e0 = bstart[b], e1 = bstart[b + 1];
    lcnt[t] = 0; __syncthreads();
    for (int i = e0 + t; i < e1; i += 512)
        atomicAdd(&lcnt[(int)pairs[i].y - lo], 1);
    __syncthreads();
    int myc = (t < nn) ? lcnt[t] : 0;
    lscan[t] = myc; __syncthreads();
    for (int off = 1; off < 512; off <<= 1) {
        int u = (t >= off) ? lscan[t - off] : 0;
        __syncthreads();
        lscan[t] += u;
        __syncthreads();
    }
    if (t < nn) {
        rowptr[lo + t] = e0 + lscan[t] - myc;
        dinv[lo + t] = rsqrtf((float)(myc + 1));   // +1 self-loop
    }
    if (t == 0 && hi == N) rowptr[N] = E;
    __syncthreads();
    lscan[t] -= myc;
    lcnt[t] = 0;
    __syncthreads();
    for (int i = e0 + t; i < e1; i += 512) {
        uint2 p = pairs[i];
        int n = (int)p.y - lo;
        int slot = atomicAdd(&lcnt[n], 1);
        int idx = lscan[n] + slot;
        if (idx < LCAP) lcol[idx] = (int)p.x;
    }
    __syncthreads();
    int cnt = e1 - e0;
    for (int i = t; i < cnt; i += 512) col[e0 + i] = lcol[i];
}

// ------- GEMM1: g1[r][c] = bf16( dinv[r] * sum_k X[r][k]*W1[k][c] ) -------

template<int D, int F, int THREADS, int RPB>
__global__ __launch_bounds__(THREADS) void k_gemm(
    const float* __restrict__ X, const float* __restrict__ W,
    const float* __restrict__ dinv, unsigned short* __restrict__ out, int N) {
    constexpr int CG = F / 4;
    constexpr int XLD = D + 4;
    __shared__ float Ws[D * F];
    __shared__ float Xs[RPB * XLD];
    int tid = threadIdx.x;
    int row0 = blockIdx.x * RPB;

    for (int i = tid; i < D * F / 4; i += THREADS)
        ((float4*)Ws)[i] = ((const float4*)W)[i];
    for (int i = tid; i < RPB * D / 4; i += THREADS) {
        int r = i / (D / 4), kk = i % (D / 4);
        int grow = row0 + r;
        float4 v = make_float4(0.f, 0.f, 0.f, 0.f);
        if (grow < N) v = *(const float4*)&X[(size_t)grow * D + kk * 4];
        *(float4*)&Xs[r * XLD + kk * 4] = v;
    }
    __syncthreads();

    int cg = tid % CG, rg = tid / CG;
    float acc[4][4] = {};
    const float* xb = &Xs[(rg * 4) * XLD];
    #pragma unroll 4
    for (int k = 0; k < D; ++k) {
        float4 w = *(float4*)&Ws[k * F + cg * 4];
        float x0 = xb[0 * XLD + k];
        float x1 = xb[1 * XLD + k];
        float x2 = xb[2 * XLD + k];
        float x3 = xb[3 * XLD + k];
        acc[0][0] += x0 * w.x; acc[0][1] += x0 * w.y; acc[0][2] += x0 * w.z; acc[0][3] += x0 * w.w;
        acc[1][0] += x1 * w.x; acc[1][1] += x1 * w.y; acc[1][2] += x1 * w.z; acc[1][3] += x1 * w.w;
        acc[2][0] += x2 * w.x; acc[2][1] += x2 * w.y; acc[2][2] += x2 * w.z; acc[2][3] += x2 * w.w;
        acc[3][0] += x3 * w.x; acc[3][1] += x3 * w.y; acc[3][2] += x3 * w.z; acc[3][3] += x3 * w.w;
    }
    #pragma unroll
    for (int i = 0; i < 4; i++) {
        int grow = row0 + rg * 4 + i;
        if (grow < N) {
            float dv = dinv[grow];
            ushort4 o;
            o.x = f2b(acc[i][0] * dv);
            o.y = f2b(acc[i][1] * dv);
            o.z = f2b(acc[i][2] * dv);
            o.w = f2b(acc[i][3] * dv);
            *(ushort4*)&out[(size_t)grow * F + cg * 4] = o;
        }
    }
}

// ---- Aggregation: 2 nodes/wave, half-wave(32 lanes) x ushort2 = one 128B row ----
// Each gather instruction moves 2 rows (256B). 8-edge batches -> 16 rows in
// flight per wave. L1: q = bf16(dinv*relu(dinv*sum + b1)); else t = bf16(dinv*sum).

template<bool L1>
__global__ __launch_bounds__(256) void k_agg(
    const unsigned short* __restrict__ gsrc, const int* __restrict__ rowptr,
    const int* __restrict__ col, const float* __restrict__ dinv,
    const float* __restrict__ b1, unsigned short* __restrict__ gout, int N) {
    int gw = (int)((blockIdx.x * 256u + threadIdx.x) >> 6);
    int lane = threadIdx.x & 63;
    int li = lane & 31;
    int node = gw * 2 + (lane >> 5);
    bool valid = node < N;
    int r0 = 0, r1 = 0;
    if (valid) { r0 = rowptr[node]; r1 = rowptr[node + 1]; }
    size_t fo = (size_t)(li * 2);
    float s0 = 0.f, s1 = 0.f;
    if (valid) {   // self-loop term
        ushort2 u = *(const ushort2*)(gsrc + (((size_t)node) << 6) + fo);
        s0 = bfu(u.x); s1 = bfu(u.y);
    }
    for (int e = r0; e < r1; e += 8) {
        int cc[8];
        #pragma unroll
        for (int j = 0; j < 8; j++) cc[j] = (e + j < r1) ? col[e + j] : -1;
        float va[8], vb[8];
        #pragma unroll
        for (int j = 0; j < 8; j++) {
            va[j] = 0.f; vb[j] = 0.f;
            if (cc[j] >= 0) {
                ushort2 u = *(const ushort2*)(gsrc + (((size_t)cc[j]) << 6) + fo);
                va[j] = bfu(u.x); vb[j] = bfu(u.y);
            }
        }
        s0 += ((va[0] + va[1]) + (va[2] + va[3])) + ((va[4] + va[5]) + (va[6] + va[7]));
        s1 += ((vb[0] + vb[1]) + (vb[2] + vb[3])) + ((vb[4] + vb[5]) + (vb[6] + vb[7]));
    }
    if (valid) {
        float dv = dinv[node];
        float o0, o1;
        if (L1) {
            o0 = dv * fmaxf(dv * s0 + b1[li * 2 + 0], 0.f);
            o1 = dv * fmaxf(dv * s1 + b1[li * 2 + 1], 0.f);
        } else {
            o0 = dv * s0;
            o1 = dv * s1;
        }
        ushort2 w;
        w.x = f2b(o0); w.y = f2b(o1);
        *(ushort2*)(gout + (((size_t)node) << 6) + fo) = w;
    }
}

// ---- gemm2s: thread-per-row t@W2 + b2, in-register log_softmax, write out ----

__global__ __launch_bounds__(256) void k_gemm2s(
    const unsigned short* __restrict__ t, const float* __restrict__ W2,
    const float* __restrict__ b2, float* __restrict__ out, int N) {
    __shared__ unsigned short Xs[256 * 72];   // bf16 rows, pad 72 (16B-aligned rows)
    __shared__ float W2s[64 * 40];
    __shared__ float b2s[40];
    int tid = threadIdx.x;
    int row0 = blockIdx.x * 256;
    for (int i = tid; i < 640; i += 256)
        ((float4*)W2s)[i] = ((const float4*)W2)[i];
    if (tid < 40) b2s[tid] = b2[tid];
    for (int c = tid; c < 2048; c += 256) {   // 256 rows x 8 16B-chunks
        int r = c >> 3, j = c & 7;
        int gr = row0 + r;
        uint4 v = make_uint4(0u, 0u, 0u, 0u);
        if (gr < N) v = *(const uint4*)(t + (((size_t)gr) << 6) + j * 8);
        *(uint4*)(Xs + r * 72 + j * 8) = v;
    }
    __syncthreads();
    int row = row0 + tid;
    if (row >= N) return;
    float acc[40];
    #pragma unroll
    for (int c = 0; c < 40; c++) acc[c] = b2s[c];
    const unsigned short* xr = Xs + tid * 72;
    for (int k = 0; k < 64; k++) {
        float x = bfu(xr[k]);
        #pragma unroll
        for (int j = 0; j < 10; j++) {
            float4 w = ((const float4*)(W2s + k * 40))[j];
            acc[4 * j + 0] += x * w.x;
            acc[4 * j + 1] += x * w.y;
            acc[4 * j + 2] += x * w.z;
            acc[4 * j + 3] += x * w.w;
        }
    }
    float m = acc[0];
    #pragma unroll
    for (int c = 1; c < 40; c++) m = fmaxf(m, acc[c]);
    float p = 0.f;
    #pragma unroll
    for (int c = 0; c < 40; c++) p += __expf(acc[c] - m);
    float l = __logf(p) + m;
    float* orow = out + (size_t)row * 40;
    #pragma unroll
    for (int j = 0; j < 10; j++) {
        float4 ov;
        ov.x = acc[4 * j + 0] - l;
        ov.y = acc[4 * j + 1] - l;
        ov.z = acc[4 * j + 2] - l;
        ov.w = acc[4 * j + 3] - l;
        *(float4*)(orow + 4 * j) = ov;
    }
}

// ---------------- launch ----------------

extern "C" void kernel_launch(void* const* d_in, const int* in_sizes, int n_in,
                              void* d_out, int out_size, void* d_ws, size_t ws_size,
                              hipStream_t stream) {
    const float* x  = (const float*)d_in[0];
    const int*   ei = (const int*)d_in[1];
    const float* W1 = (const float*)d_in[2];
    const float* b1 = (const float*)d_in[3];
    const float* W2 = (const float*)d_in[4];
    const float* b2 = (const float*)d_in[5];
    float* out = (float*)d_out;

    const int N = in_sizes[0] / 128;
    const int E = in_sizes[1] / 2;
    const int B = (N + NPB - 1) >> NPB_SHIFT;
    const int* src = ei;
    const int* dst = ei + E;

    char* w = (char*)d_ws;
    size_t off = 0;
    auto alloc = [&](size_t bytes) -> char* {
        char* p = w + off;
        off += (bytes + 255) & ~(size_t)255;
        return p;
    };
    int*   bcnt   = (int*)alloc((size_t)(B + 1) * 4);
    int*   bstart = (int*)alloc((size_t)(B + 1) * 4);
    int*   cursor = (int*)alloc((size_t)B * 4);
    int*   rowptr = (int*)alloc((size_t)(N + 1) * 4);
    float* dinv   = (float*)alloc((size_t)N * 4);
    int*   col    = (int*)alloc((size_t)E * 4 + 256);
    // sh: pairs (E*8B) during build; then g1 (N*64*2B); then t (N*64*2B)
    size_t shbytes = (size_t)E * 8 > (size_t)N * 64 * 2 ? (size_t)E * 8 : (size_t)N * 64 * 2;
    char*  sh     = alloc(shbytes);
    unsigned short* q = (unsigned short*)alloc((size_t)N * 64 * 2);
    uint2* pairs  = (uint2*)sh;
    unsigned short* g1 = (unsigned short*)sh;   // pairs dead after k_p2
    unsigned short* t  = (unsigned short*)sh;   // g1 dead after agg<true>

    k_zeroB<<<1, 256, 0, stream>>>(bcnt, B);
    k_p1count<<<256, 256, 0, stream>>>(dst, E, B, bcnt);
    k_scanB<<<1, 256, 0, stream>>>(bcnt, B, E, bstart, cursor);
    int nch = (E + P1C - 1) / P1C;
    k_p1place<<<nch, 256, 0, stream>>>(src, dst, E, B, cursor, pairs);
    k_p2<<<B, 512, 0, stream>>>(pairs, bstart, rowptr, dinv, col, N, E);

    int nwaves = (N + 1) / 2;
    int aggblocks = (nwaves + 3) / 4;

    // layer 1: g1 = bf16(dinv*(x@W1)); q = bf16(dinv*relu(dinv*(sum g1)+b1))
    k_gemm<128, 64, 256, 64><<<(N + 63) / 64, 256, 0, stream>>>(x, W1, dinv, g1, N);
    k_agg<true><<<aggblocks, 256, 0, stream>>>(g1, rowptr, col, dinv, b1, q, N);

    // layer 2 (commuted): t = bf16(dinv*(sum q)); out = log_softmax(t@W2 + b2)
    k_agg<false><<<aggblocks, 256, 0, stream>>>(q, rowptr, col, dinv, b1, t, N);
    k_gemm2s<<<(N + 255) / 256, 256, 0, stream>>>(t, W2, b2, out, N);
}

// Round 11
// 192.956 us; speedup vs baseline: 1.2594x; 1.2594x over previous
//
#include <hip/hip_runtime.h>
#include <hip/hip_bf16.h>
#include <math.h>

typedef long long i64;

__device__ __forceinline__ float bfu(unsigned short u) {
    union { unsigned int i; float f; } v; v.i = ((unsigned)u) << 16; return v.f;
}
__device__ __forceinline__ unsigned short f2b(float f) {
    __hip_bfloat16 h = __float2bfloat16(f);
    return *reinterpret_cast<unsigned short*>(&h);
}

// ================= CSR build: 2-phase radix partition by dst =================
#define NPB_SHIFT 9
#define NPB 512
#define LCAP 16384
#define P1C 4096

__global__ void k_zeroB(int* __restrict__ bcnt, int B) {
    int t = threadIdx.x;
    if (t <= B) bcnt[t] = 0;
}

__global__ __launch_bounds__(256) void k_p1count(
    const int* __restrict__ dst, int E, int B, int* __restrict__ bcnt) {
    __shared__ int lb[256];
    int t = threadIdx.x;
    lb[t] = 0; __syncthreads();
    int cpb = (E + gridDim.x - 1) / gridDim.x;
    int s0 = blockIdx.x * cpb, s1 = min(E, s0 + cpb);
    for (int i = s0 + t; i < s1; i += 256)
        atomicAdd(&lb[dst[i] >> NPB_SHIFT], 1);
    __syncthreads();
    if (t < B && lb[t]) atomicAdd(&bcnt[t], lb[t]);
}

__global__ void k_scanB(const int* __restrict__ bcnt, int B, int E,
                        int* __restrict__ bstart, int* __restrict__ cursor) {
    __shared__ int s[256];
    int t = threadIdx.x;
    int v = (t < B) ? bcnt[t] : 0;
    s[t] = v; __syncthreads();
    for (int off = 1; off < 256; off <<= 1) {
        int u = (t >= off) ? s[t - off] : 0;
        __syncthreads();
        s[t] += u;
        __syncthreads();
    }
    int excl = s[t] - v;
    if (t < B) { bstart[t] = excl; cursor[t] = excl; }
    if (t == 0) bstart[B] = E;
}

__global__ __launch_bounds__(256) void k_p1place(
    const int* __restrict__ src, const int* __restrict__ dst, int E, int B,
    int* __restrict__ cursor, uint2* __restrict__ pairs) {
    __shared__ int ls_s[P1C];
    __shared__ int ls_d[P1C];
    __shared__ int lb[256];
    __shared__ int lbase[256];
    int t = threadIdx.x;
    int s0 = blockIdx.x * P1C, s1 = min(E, s0 + P1C), n = s1 - s0;
    lb[t] = 0; __syncthreads();
    for (int i = t; i < n; i += 256) {
        int d = dst[s0 + i];
        ls_d[i] = d;
        ls_s[i] = src[s0 + i];
        atomicAdd(&lb[d >> NPB_SHIFT], 1);
    }
    __syncthreads();
    if (t < B && lb[t]) lbase[t] = atomicAdd(&cursor[t], lb[t]);
    __syncthreads();
    lb[t] = 0; __syncthreads();
    for (int i = t; i < n; i += 256) {
        int d = ls_d[i];
        int bkt = d >> NPB_SHIFT;
        int slot = atomicAdd(&lb[bkt], 1);
        pairs[lbase[bkt] + slot] = make_uint2((unsigned)ls_s[i], (unsigned)d);
    }
}

__global__ __launch_bounds__(512) void k_p2(
    const uint2* __restrict__ pairs, const int* __restrict__ bstart,
    int* __restrict__ rowptr, float* __restrict__ dinv,
    int* __restrict__ col, int N, int E) {
    __shared__ int lcnt[NPB];
    __shared__ int lscan[NPB];
    __shared__ int lcol[LCAP];
    int b = blockIdx.x, t = threadIdx.x;
    int lo = b << NPB_SHIFT, hi = min(N, lo + NPB), nn = hi - lo;
    int e0 = bstart[b], e1 = bstart[b + 1];
    lcnt[t] = 0; __syncthreads();
    for (int i = e0 + t; i < e1; i += 512)
        atomicAdd(&lcnt[(int)pairs[i].y - lo], 1);
    __syncthreads();
    int myc = (t < nn) ? lcnt[t] : 0;
    lscan[t] = myc; __syncthreads();
    for (int off = 1; off < 512; off <<= 1) {
        int u = (t >= off) ? lscan[t - off] : 0;
        __syncthreads();
        lscan[t] += u;
        __syncthreads();
    }
    if (t < nn) {
        rowptr[lo + t] = e0 + lscan[t] - myc;
        dinv[lo + t] = rsqrtf((float)(myc + 1));   // +1 self-loop
    }
    if (t == 0 && hi == N) rowptr[N] = E;
    __syncthreads();
    lscan[t] -= myc;
    lcnt[t] = 0;
    __syncthreads();
    for (int i = e0 + t; i < e1; i += 512) {
        uint2 p = pairs[i];
        int n = (int)p.y - lo;
        int slot = atomicAdd(&lcnt[n], 1);
        int idx = lscan[n] + slot;
        if (idx < LCAP) lcol[idx] = (int)p.x;
    }
    __syncthreads();
    int cnt = e1 - e0;
    for (int i = t; i < cnt; i += 512) col[e0 + i] = lcol[i];
}

// ------- GEMM1: g1[r][c] = bf16( dinv[r] * sum_k X[r][k]*W1[k][c] ) -------

template<int D, int F, int THREADS, int RPB>
__global__ __launch_bounds__(THREADS) void k_gemm(
    const float* __restrict__ X, const float* __restrict__ W,
    const float* __restrict__ dinv, unsigned short* __restrict__ out, int N) {
    constexpr int CG = F / 4;
    constexpr int XLD = D + 4;
    __shared__ float Ws[D * F];
    __shared__ float Xs[RPB * XLD];
    int tid = threadIdx.x;
    int row0 = blockIdx.x * RPB;

    for (int i = tid; i < D * F / 4; i += THREADS)
        ((float4*)Ws)[i] = ((const float4*)W)[i];
    for (int i = tid; i < RPB * D / 4; i += THREADS) {
        int r = i / (D / 4), kk = i % (D / 4);
        int grow = row0 + r;
        float4 v = make_float4(0.f, 0.f, 0.f, 0.f);
        if (grow < N) v = *(const float4*)&X[(size_t)grow * D + kk * 4];
        *(float4*)&Xs[r * XLD + kk * 4] = v;
    }
    __syncthreads();

    int cg = tid % CG, rg = tid / CG;
    float acc[4][4] = {};
    const float* xb = &Xs[(rg * 4) * XLD];
    #pragma unroll 4
    for (int k = 0; k < D; ++k) {
        float4 w = *(float4*)&Ws[k * F + cg * 4];
        float x0 = xb[0 * XLD + k];
        float x1 = xb[1 * XLD + k];
        float x2 = xb[2 * XLD + k];
        float x3 = xb[3 * XLD + k];
        acc[0][0] += x0 * w.x; acc[0][1] += x0 * w.y; acc[0][2] += x0 * w.z; acc[0][3] += x0 * w.w;
        acc[1][0] += x1 * w.x; acc[1][1] += x1 * w.y; acc[1][2] += x1 * w.z; acc[1][3] += x1 * w.w;
        acc[2][0] += x2 * w.x; acc[2][1] += x2 * w.y; acc[2][2] += x2 * w.z; acc[2][3] += x2 * w.w;
        acc[3][0] += x3 * w.x; acc[3][1] += x3 * w.y; acc[3][2] += x3 * w.z; acc[3][3] += x3 * w.w;
    }
    #pragma unroll
    for (int i = 0; i < 4; i++) {
        int grow = row0 + rg * 4 + i;
        if (grow < N) {
            float dv = dinv[grow];
            ushort4 o;
            o.x = f2b(acc[i][0] * dv);
            o.y = f2b(acc[i][1] * dv);
            o.z = f2b(acc[i][2] * dv);
            o.w = f2b(acc[i][3] * dv);
            *(ushort4*)&out[(size_t)grow * F + cg * 4] = o;
        }
    }
}

// ---- Aggregation: 2 nodes/wave, half-wave(32 lanes) x ushort2 = one 128B row ----
// R10 regression root-cause: depth dropped 16->8 when packing 2 nodes/wave.
// Fix: 16 outstanding gathers/wave (4KB in flight), unconditional main batch.

template<bool L1>
__global__ __launch_bounds__(256) void k_agg(
    const unsigned short* __restrict__ gsrc, const int* __restrict__ rowptr,
    const int* __restrict__ col, const float* __restrict__ dinv,
    const float* __restrict__ b1, unsigned short* __restrict__ gout, int N) {
    int gw = (int)((blockIdx.x * 256u + threadIdx.x) >> 6);
    int lane = threadIdx.x & 63;
    int li = lane & 31;
    int node = gw * 2 + (lane >> 5);
    bool valid = node < N;
    int r0 = 0, r1 = 0;
    if (valid) { r0 = rowptr[node]; r1 = rowptr[node + 1]; }
    size_t fo = (size_t)(li * 2);
    float s0 = 0.f, s1 = 0.f;
    if (valid) {   // self-loop term
        ushort2 u = *(const ushort2*)(gsrc + (((size_t)node) << 6) + fo);
        s0 = bfu(u.x); s1 = bfu(u.y);
    }
    int e = r0;
    for (; e + 16 <= r1; e += 16) {
        int cc[16];
        #pragma unroll
        for (int j = 0; j < 16; j++) cc[j] = col[e + j];
        float va[16], vb[16];
        #pragma unroll
        for (int j = 0; j < 16; j++) {
            ushort2 u = *(const ushort2*)(gsrc + (((size_t)cc[j]) << 6) + fo);
            va[j] = bfu(u.x); vb[j] = bfu(u.y);
        }
        #pragma unroll
        for (int s = 1; s < 16; s <<= 1)
            #pragma unroll
            for (int j = 0; j < 16; j += 2 * s) { va[j] += va[j + s]; vb[j] += vb[j + s]; }
        s0 += va[0]; s1 += vb[0];
    }
    for (; e + 4 <= r1; e += 4) {
        int c0 = col[e], c1 = col[e + 1], c2 = col[e + 2], c3 = col[e + 3];
        ushort2 u0 = *(const ushort2*)(gsrc + (((size_t)c0) << 6) + fo);
        ushort2 u1 = *(const ushort2*)(gsrc + (((size_t)c1) << 6) + fo);
        ushort2 u2 = *(const ushort2*)(gsrc + (((size_t)c2) << 6) + fo);
        ushort2 u3 = *(const ushort2*)(gsrc + (((size_t)c3) << 6) + fo);
        s0 += (bfu(u0.x) + bfu(u1.x)) + (bfu(u2.x) + bfu(u3.x));
        s1 += (bfu(u0.y) + bfu(u1.y)) + (bfu(u2.y) + bfu(u3.y));
    }
    for (; e < r1; ++e) {
        ushort2 u = *(const ushort2*)(gsrc + (((size_t)col[e]) << 6) + fo);
        s0 += bfu(u.x); s1 += bfu(u.y);
    }
    if (valid) {
        float dv = dinv[node];
        float o0, o1;
        if (L1) {
            o0 = dv * fmaxf(dv * s0 + b1[li * 2 + 0], 0.f);
            o1 = dv * fmaxf(dv * s1 + b1[li * 2 + 1], 0.f);
        } else {
            o0 = dv * s0;
            o1 = dv * s1;
        }
        ushort2 w;
        w.x = f2b(o0); w.y = f2b(o1);
        *(ushort2*)(gout + (((size_t)node) << 6) + fo) = w;
    }
}

// ---- gemm2s: thread-per-row t@W2 + b2, in-register log_softmax, write out ----

__global__ __launch_bounds__(256) void k_gemm2s(
    const unsigned short* __restrict__ t, const float* __restrict__ W2,
    const float* __restrict__ b2, float* __restrict__ out, int N) {
    __shared__ unsigned short Xs[256 * 72];   // bf16 rows, pad 72 (16B-aligned rows)
    __shared__ float W2s[64 * 40];
    __shared__ float b2s[40];
    int tid = threadIdx.x;
    int row0 = blockIdx.x * 256;
    for (int i = tid; i < 640; i += 256)
        ((float4*)W2s)[i] = ((const float4*)W2)[i];
    if (tid < 40) b2s[tid] = b2[tid];
    for (int c = tid; c < 2048; c += 256) {   // 256 rows x 8 16B-chunks
        int r = c >> 3, j = c & 7;
        int gr = row0 + r;
        uint4 v = make_uint4(0u, 0u, 0u, 0u);
        if (gr < N) v = *(const uint4*)(t + (((size_t)gr) << 6) + j * 8);
        *(uint4*)(Xs + r * 72 + j * 8) = v;
    }
    __syncthreads();
    int row = row0 + tid;
    if (row >= N) return;
    float acc[40];
    #pragma unroll
    for (int c = 0; c < 40; c++) acc[c] = b2s[c];
    const unsigned short* xr = Xs + tid * 72;
    for (int k = 0; k < 64; k++) {
        float x = bfu(xr[k]);
        #pragma unroll
        for (int j = 0; j < 10; j++) {
            float4 w = ((const float4*)(W2s + k * 40))[j];
            acc[4 * j + 0] += x * w.x;
            acc[4 * j + 1] += x * w.y;
            acc[4 * j + 2] += x * w.z;
            acc[4 * j + 3] += x * w.w;
        }
    }
    float m = acc[0];
    #pragma unroll
    for (int c = 1; c < 40; c++) m = fmaxf(m, acc[c]);
    float p = 0.f;
    #pragma unroll
    for (int c = 0; c < 40; c++) p += __expf(acc[c] - m);
    float l = __logf(p) + m;
    float* orow = out + (size_t)row * 40;
    #pragma unroll
    for (int j = 0; j < 10; j++) {
        float4 ov;
        ov.x = acc[4 * j + 0] - l;
        ov.y = acc[4 * j + 1] - l;
        ov.z = acc[4 * j + 2] - l;
        ov.w = acc[4 * j + 3] - l;
        *(float4*)(orow + 4 * j) = ov;
    }
}

// ---------------- launch ----------------

extern "C" void kernel_launch(void* const* d_in, const int* in_sizes, int n_in,
                              void* d_out, int out_size, void* d_ws, size_t ws_size,
                              hipStream_t stream) {
    const float* x  = (const float*)d_in[0];
    const int*   ei = (const int*)d_in[1];
    const float* W1 = (const float*)d_in[2];
    const float* b1 = (const float*)d_in[3];
    const float* W2 = (const float*)d_in[4];
    const float* b2 = (const float*)d_in[5];
    float* out = (float*)d_out;

    const int N = in_sizes[0] / 128;
    const int E = in_sizes[1] / 2;
    const int B = (N + NPB - 1) >> NPB_SHIFT;
    const int* src = ei;
    const int* dst = ei + E;

    char* w = (char*)d_ws;
    size_t off = 0;
    auto alloc = [&](size_t bytes) -> char* {
        char* p = w + off;
        off += (bytes + 255) & ~(size_t)255;
        return p;
    };
    int*   bcnt   = (int*)alloc((size_t)(B + 1) * 4);
    int*   bstart = (int*)alloc((size_t)(B + 1) * 4);
    int*   cursor = (int*)alloc((size_t)B * 4);
    int*   rowptr = (int*)alloc((size_t)(N + 1) * 4);
    float* dinv   = (float*)alloc((size_t)N * 4);
    int*   col    = (int*)alloc((size_t)E * 4 + 256);
    size_t shbytes = (size_t)E * 8 > (size_t)N * 64 * 2 ? (size_t)E * 8 : (size_t)N * 64 * 2;
    char*  sh     = alloc(shbytes);
    unsigned short* q = (unsigned short*)alloc((size_t)N * 64 * 2);
    uint2* pairs  = (uint2*)sh;
    unsigned short* g1 = (unsigned short*)sh;   // pairs dead after k_p2
    unsigned short* t  = (unsigned short*)sh;   // g1 dead after agg<true>

    k_zeroB<<<1, 256, 0, stream>>>(bcnt, B);
    k_p1count<<<256, 256, 0, stream>>>(dst, E, B, bcnt);
    k_scanB<<<1, 256, 0, stream>>>(bcnt, B, E, bstart, cursor);
    int nch = (E + P1C - 1) / P1C;
    k_p1place<<<nch, 256, 0, stream>>>(src, dst, E, B, cursor, pairs);
    k_p2<<<B, 512, 0, stream>>>(pairs, bstart, rowptr, dinv, col, N, E);

    int nwaves = (N + 1) / 2;
    int aggblocks = (nwaves + 3) / 4;

    // layer 1: g1 = bf16(dinv*(x@W1)); q = bf16(dinv*relu(dinv*(sum g1)+b1))
    k_gemm<128, 64, 256, 64><<<(N + 63) / 64, 256, 0, stream>>>(x, W1, dinv, g1, N);
    k_agg<true><<<aggblocks, 256, 0, stream>>>(g1, rowptr, col, dinv, b1, q, N);

    // layer 2 (commuted): t = bf16(dinv*(sum q)); out = log_softmax(t@W2 + b2)
    k_agg<false><<<aggblocks, 256, 0, stream>>>(q, rowptr, col, dinv, b1, t, N);
    k_gemm2s<<<(N + 255) / 256, 256, 0, stream>>>(t, W2, b2, out, N);
}

// Round 12
// 181.674 us; speedup vs baseline: 1.3376x; 1.0621x over previous
//
#include <hip/hip_runtime.h>
#include <hip/hip_bf16.h>
#include <math.h>

typedef long long i64;
typedef __attribute__((ext_vector_type(8))) short short8v;
typedef __attribute__((ext_vector_type(4))) float f32x4;

__device__ __forceinline__ float bfu(unsigned short u) {
    union { unsigned int i; float f; } v; v.i = ((unsigned)u) << 16; return v.f;
}
__device__ __forceinline__ unsigned short f2b(float f) {
    __hip_bfloat16 h = __float2bfloat16(f);
    return *reinterpret_cast<unsigned short*>(&h);
}

// ================= CSR build: 2-phase radix partition by dst =================
#define NPB_SHIFT 9
#define NPB 512
#define LCAP 16384
#define P1C 4096

__global__ void k_zeroB(int* __restrict__ bcnt, int B) {
    int t = threadIdx.x;
    if (t <= B) bcnt[t] = 0;
}

__global__ __launch_bounds__(256) void k_p1count(
    const int* __restrict__ dst, int E, int B, int* __restrict__ bcnt) {
    __shared__ int lb[256];
    int t = threadIdx.x;
    lb[t] = 0; __syncthreads();
    int cpb = (E + gridDim.x - 1) / gridDim.x;
    int s0 = blockIdx.x * cpb, s1 = min(E, s0 + cpb);
    for (int i = s0 + t; i < s1; i += 256)
        atomicAdd(&lb[dst[i] >> NPB_SHIFT], 1);
    __syncthreads();
    if (t < B && lb[t]) atomicAdd(&bcnt[t], lb[t]);
}

__global__ void k_scanB(const int* __restrict__ bcnt, int B, int E,
                        int* __restrict__ bstart, int* __restrict__ cursor) {
    __shared__ int s[256];
    int t = threadIdx.x;
    int v = (t < B) ? bcnt[t] : 0;
    s[t] = v; __syncthreads();
    for (int off = 1; off < 256; off <<= 1) {
        int u = (t >= off) ? s[t - off] : 0;
        __syncthreads();
        s[t] += u;
        __syncthreads();
    }
    int excl = s[t] - v;
    if (t < B) { bstart[t] = excl; cursor[t] = excl; }
    if (t == 0) bstart[B] = E;
}

__global__ __launch_bounds__(256) void k_p1place(
    const int* __restrict__ src, const int* __restrict__ dst, int E, int B,
    int* __restrict__ cursor, uint2* __restrict__ pairs) {
    __shared__ int ls_s[P1C];
    __shared__ int ls_d[P1C];
    __shared__ int lb[256];
    __shared__ int lbase[256];
    int t = threadIdx.x;
    int s0 = blockIdx.x * P1C, s1 = min(E, s0 + P1C), n = s1 - s0;
    lb[t] = 0; __syncthreads();
    for (int i = t; i < n; i += 256) {
        int d = dst[s0 + i];
        ls_d[i] = d;
        ls_s[i] = src[s0 + i];
        atomicAdd(&lb[d >> NPB_SHIFT], 1);
    }
    __syncthreads();
    if (t < B && lb[t]) lbase[t] = atomicAdd(&cursor[t], lb[t]);
    __syncthreads();
    lb[t] = 0; __syncthreads();
    for (int i = t; i < n; i += 256) {
        int d = ls_d[i];
        int bkt = d >> NPB_SHIFT;
        int slot = atomicAdd(&lb[bkt], 1);
        pairs[lbase[bkt] + slot] = make_uint2((unsigned)ls_s[i], (unsigned)d);
    }
}

__global__ __launch_bounds__(512) void k_p2(
    const uint2* __restrict__ pairs, const int* __restrict__ bstart,
    int* __restrict__ rowptr, float* __restrict__ dinv,
    int* __restrict__ col, int N, int E) {
    __shared__ int lcnt[NPB];
    __shared__ int lscan[NPB];
    __shared__ int lcol[LCAP];
    int b = blockIdx.x, t = threadIdx.x;
    int lo = b << NPB_SHIFT, hi = min(N, lo + NPB), nn = hi - lo;
    int e0 = bstart[b], e1 = bstart[b + 1];
    lcnt[t] = 0; __syncthreads();
    for (int i = e0 + t; i < e1; i += 512)
        atomicAdd(&lcnt[(int)pairs[i].y - lo], 1);
    __syncthreads();
    int myc = (t < nn) ? lcnt[t] : 0;
    lscan[t] = myc; __syncthreads();
    for (int off = 1; off < 512; off <<= 1) {
        int u = (t >= off) ? lscan[t - off] : 0;
        __syncthreads();
        lscan[t] += u;
        __syncthreads();
    }
    if (t < nn) {
        rowptr[lo + t] = e0 + lscan[t] - myc;
        dinv[lo + t] = rsqrtf((float)(myc + 1));   // +1 self-loop
    }
    if (t == 0 && hi == N) rowptr[N] = E;
    __syncthreads();
    lscan[t] -= myc;
    lcnt[t] = 0;
    __syncthreads();
    for (int i = e0 + t; i < e1; i += 512) {
        uint2 p = pairs[i];
        int n = (int)p.y - lo;
        int slot = atomicAdd(&lcnt[n], 1);
        int idx = lscan[n] + slot;
        if (idx < LCAP) lcol[idx] = (int)p.x;
    }
    __syncthreads();
    int cnt = e1 - e0;
    for (int i = t; i < cnt; i += 512) col[e0 + i] = lcol[i];
}

// ------- GEMM1 (MFMA bf16): g1[r][c] = bf16( dinv[r] * (x @ W1)[r][c] ) -------
// 128x64 tile, K=128 staged fully in LDS (X bf16 32KB + W1^T bf16 16KB = 48KB
// -> 3 blocks/CU). Both tiles 256B/row -> XOR-swizzle byte^=(row&7)<<4 (T2).
// Frags (16x16x32): A/B idx=lane&15, k=(lane>>4)*8+j; C/D col=lane&15,
// row=(lane>>4)*4+reg (m89-verified).

__global__ __launch_bounds__(256) void k_gemm1m(
    const float* __restrict__ X, const float* __restrict__ W,
    const float* __restrict__ dinv, unsigned short* __restrict__ out, int N) {
    __shared__ unsigned short Xs[128 * 128];   // 32 KB
    __shared__ unsigned short Wt[64 * 128];    // 16 KB (W^T)
    int tid = threadIdx.x;
    int row0 = blockIdx.x << 7;

    // stage W^T bf16 swizzled: W[k][n] (coalesced float4) -> Wt[n][k]
    for (int i = tid; i < 2048; i += 256) {
        float4 v = *(const float4*)(W + i * 4);
        int k = (i * 4) >> 6, n = (i * 4) & 63;
        int kb = k * 2;
        *(unsigned short*)((char*)Wt + (n + 0) * 256 + (kb ^ (((n + 0) & 7) << 4))) = f2b(v.x);
        *(unsigned short*)((char*)Wt + (n + 1) * 256 + (kb ^ (((n + 1) & 7) << 4))) = f2b(v.y);
        *(unsigned short*)((char*)Wt + (n + 2) * 256 + (kb ^ (((n + 2) & 7) << 4))) = f2b(v.z);
        *(unsigned short*)((char*)Wt + (n + 3) * 256 + (kb ^ (((n + 3) & 7) << 4))) = f2b(v.w);
    }
    // stage X tile bf16 swizzled (coalesced float4 global reads)
    for (int i = tid; i < 4096; i += 256) {
        int r = i >> 5, c4 = i & 31;
        int gr = row0 + r;
        float4 v = make_float4(0.f, 0.f, 0.f, 0.f);
        if (gr < N) v = *(const float4*)(X + (size_t)gr * 128 + c4 * 4);
        ushort4 h;
        h.x = f2b(v.x); h.y = f2b(v.y); h.z = f2b(v.z); h.w = f2b(v.w);
        *(ushort4*)((char*)Xs + r * 256 + ((c4 * 8) ^ ((r & 7) << 4))) = h;
    }
    __syncthreads();

    int wid = tid >> 6, lane = tid & 63;
    int l15 = lane & 15, lg = lane >> 4;
    int wrow = wid * 32;                       // wave's 32-row band

    f32x4 acc[2][4];
    #pragma unroll
    for (int fr = 0; fr < 2; fr++)
        #pragma unroll
        for (int fc = 0; fc < 4; fc++) acc[fr][fc] = (f32x4){0.f, 0.f, 0.f, 0.f};

    #pragma unroll
    for (int ks = 0; ks < 4; ks++) {
        int kbyte = ks * 64 + lg * 16;
        int ra0 = wrow + l15, ra1 = wrow + 16 + l15;
        short8v a0 = *(short8v*)((char*)Xs + ra0 * 256 + (kbyte ^ ((ra0 & 7) << 4)));
        short8v a1 = *(short8v*)((char*)Xs + ra1 * 256 + (kbyte ^ ((ra1 & 7) << 4)));
        int swb = kbyte ^ ((l15 & 7) << 4);    // (n+16k)&7 == n&7
        short8v b0 = *(short8v*)((char*)Wt + (l15) * 256 + swb);
        short8v b1 = *(short8v*)((char*)Wt + (16 + l15) * 256 + swb);
        short8v b2 = *(short8v*)((char*)Wt + (32 + l15) * 256 + swb);
        short8v b3 = *(short8v*)((char*)Wt + (48 + l15) * 256 + swb);
        acc[0][0] = __builtin_amdgcn_mfma_f32_16x16x32_bf16(a0, b0, acc[0][0], 0, 0, 0);
        acc[0][1] = __builtin_amdgcn_mfma_f32_16x16x32_bf16(a0, b1, acc[0][1], 0, 0, 0);
        acc[0][2] = __builtin_amdgcn_mfma_f32_16x16x32_bf16(a0, b2, acc[0][2], 0, 0, 0);
        acc[0][3] = __builtin_amdgcn_mfma_f32_16x16x32_bf16(a0, b3, acc[0][3], 0, 0, 0);
        acc[1][0] = __builtin_amdgcn_mfma_f32_16x16x32_bf16(a1, b0, acc[1][0], 0, 0, 0);
        acc[1][1] = __builtin_amdgcn_mfma_f32_16x16x32_bf16(a1, b1, acc[1][1], 0, 0, 0);
        acc[1][2] = __builtin_amdgcn_mfma_f32_16x16x32_bf16(a1, b2, acc[1][2], 0, 0, 0);
        acc[1][3] = __builtin_amdgcn_mfma_f32_16x16x32_bf16(a1, b3, acc[1][3], 0, 0, 0);
    }

    float dv[2][4];
    #pragma unroll
    for (int fr = 0; fr < 2; fr++)
        #pragma unroll
        for (int reg = 0; reg < 4; reg++) {
            int grow = row0 + wrow + fr * 16 + lg * 4 + reg;
            dv[fr][reg] = (grow < N) ? dinv[grow] : 0.f;
        }
    #pragma unroll
    for (int fr = 0; fr < 2; fr++)
        #pragma unroll
        for (int fc = 0; fc < 4; fc++)
            #pragma unroll
            for (int reg = 0; reg < 4; reg++) {
                int grow = row0 + wrow + fr * 16 + lg * 4 + reg;
                if (grow < N)
                    out[(size_t)grow * 64 + fc * 16 + l15] = f2b(acc[fr][fc][reg] * dv[fr][reg]);
            }
}

// ---- Aggregation: 2 nodes/wave, half-wave(32 lanes) x ushort2 = one 128B row ----

template<bool L1>
__global__ __launch_bounds__(256) void k_agg(
    const unsigned short* __restrict__ gsrc, const int* __restrict__ rowptr,
    const int* __restrict__ col, const float* __restrict__ dinv,
    const float* __restrict__ b1, unsigned short* __restrict__ gout, int N) {
    int gw = (int)((blockIdx.x * 256u + threadIdx.x) >> 6);
    int lane = threadIdx.x & 63;
    int li = lane & 31;
    int node = gw * 2 + (lane >> 5);
    bool valid = node < N;
    int r0 = 0, r1 = 0;
    if (valid) { r0 = rowptr[node]; r1 = rowptr[node + 1]; }
    size_t fo = (size_t)(li * 2);
    float s0 = 0.f, s1 = 0.f;
    if (valid) {   // self-loop term
        ushort2 u = *(const ushort2*)(gsrc + (((size_t)node) << 6) + fo);
        s0 = bfu(u.x); s1 = bfu(u.y);
    }
    int e = r0;
    for (; e + 16 <= r1; e += 16) {
        int cc[16];
        #pragma unroll
        for (int j = 0; j < 16; j++) cc[j] = col[e + j];
        float va[16], vb[16];
        #pragma unroll
        for (int j = 0; j < 16; j++) {
            ushort2 u = *(const ushort2*)(gsrc + (((size_t)cc[j]) << 6) + fo);
            va[j] = bfu(u.x); vb[j] = bfu(u.y);
        }
        #pragma unroll
        for (int s = 1; s < 16; s <<= 1)
            #pragma unroll
            for (int j = 0; j < 16; j += 2 * s) { va[j] += va[j + s]; vb[j] += vb[j + s]; }
        s0 += va[0]; s1 += vb[0];
    }
    for (; e + 4 <= r1; e += 4) {
        int c0 = col[e], c1 = col[e + 1], c2 = col[e + 2], c3 = col[e + 3];
        ushort2 u0 = *(const ushort2*)(gsrc + (((size_t)c0) << 6) + fo);
        ushort2 u1 = *(const ushort2*)(gsrc + (((size_t)c1) << 6) + fo);
        ushort2 u2 = *(const ushort2*)(gsrc + (((size_t)c2) << 6) + fo);
        ushort2 u3 = *(const ushort2*)(gsrc + (((size_t)c3) << 6) + fo);
        s0 += (bfu(u0.x) + bfu(u1.x)) + (bfu(u2.x) + bfu(u3.x));
        s1 += (bfu(u0.y) + bfu(u1.y)) + (bfu(u2.y) + bfu(u3.y));
    }
    for (; e < r1; ++e) {
        ushort2 u = *(const ushort2*)(gsrc + (((size_t)col[e]) << 6) + fo);
        s0 += bfu(u.x); s1 += bfu(u.y);
    }
    if (valid) {
        float dvn = dinv[node];
        float o0, o1;
        if (L1) {
            o0 = dvn * fmaxf(dvn * s0 + b1[li * 2 + 0], 0.f);
            o1 = dvn * fmaxf(dvn * s1 + b1[li * 2 + 1], 0.f);
        } else {
            o0 = dvn * s0;
            o1 = dvn * s1;
        }
        ushort2 w;
        w.x = f2b(o0); w.y = f2b(o1);
        *(ushort2*)(gout + (((size_t)node) << 6) + fo) = w;
    }
}

// ---- gemm2s: thread-per-row t@W2 + b2, in-register log_softmax, write out ----

__global__ __launch_bounds__(256) void k_gemm2s(
    const unsigned short* __restrict__ t, const float* __restrict__ W2,
    const float* __restrict__ b2, float* __restrict__ out, int N) {
    __shared__ unsigned short Xs[256 * 72];
    __shared__ float W2s[64 * 40];
    __shared__ float b2s[40];
    int tid = threadIdx.x;
    int row0 = blockIdx.x * 256;
    for (int i = tid; i < 640; i += 256)
        ((float4*)W2s)[i] = ((const float4*)W2)[i];
    if (tid < 40) b2s[tid] = b2[tid];
    for (int c = tid; c < 2048; c += 256) {
        int r = c >> 3, j = c & 7;
        int gr = row0 + r;
        uint4 v = make_uint4(0u, 0u, 0u, 0u);
        if (gr < N) v = *(const uint4*)(t + (((size_t)gr) << 6) + j * 8);
        *(uint4*)(Xs + r * 72 + j * 8) = v;
    }
    __syncthreads();
    int row = row0 + tid;
    if (row >= N) return;
    float acc[40];
    #pragma unroll
    for (int c = 0; c < 40; c++) acc[c] = b2s[c];
    const unsigned short* xr = Xs + tid * 72;
    for (int k = 0; k < 64; k++) {
        float x = bfu(xr[k]);
        #pragma unroll
        for (int j = 0; j < 10; j++) {
            float4 w = ((const float4*)(W2s + k * 40))[j];
            acc[4 * j + 0] += x * w.x;
            acc[4 * j + 1] += x * w.y;
            acc[4 * j + 2] += x * w.z;
            acc[4 * j + 3] += x * w.w;
        }
    }
    float m = acc[0];
    #pragma unroll
    for (int c = 1; c < 40; c++) m = fmaxf(m, acc[c]);
    float p = 0.f;
    #pragma unroll
    for (int c = 0; c < 40; c++) p += __expf(acc[c] - m);
    float l = __logf(p) + m;
    float* orow = out + (size_t)row * 40;
    #pragma unroll
    for (int j = 0; j < 10; j++) {
        float4 ov;
        ov.x = acc[4 * j + 0] - l;
        ov.y = acc[4 * j + 1] - l;
        ov.z = acc[4 * j + 2] - l;
        ov.w = acc[4 * j + 3] - l;
        *(float4*)(orow + 4 * j) = ov;
    }
}

// ---------------- launch ----------------

extern "C" void kernel_launch(void* const* d_in, const int* in_sizes, int n_in,
                              void* d_out, int out_size, void* d_ws, size_t ws_size,
                              hipStream_t stream) {
    const float* x  = (const float*)d_in[0];
    const int*   ei = (const int*)d_in[1];
    const float* W1 = (const float*)d_in[2];
    const float* b1 = (const float*)d_in[3];
    const float* W2 = (const float*)d_in[4];
    const float* b2 = (const float*)d_in[5];
    float* out = (float*)d_out;

    const int N = in_sizes[0] / 128;
    const int E = in_sizes[1] / 2;
    const int B = (N + NPB - 1) >> NPB_SHIFT;
    const int* src = ei;
    const int* dst = ei + E;

    char* w = (char*)d_ws;
    size_t off = 0;
    auto alloc = [&](size_t bytes) -> char* {
        char* p = w + off;
        off += (bytes + 255) & ~(size_t)255;
        return p;
    };
    int*   bcnt   = (int*)alloc((size_t)(B + 1) * 4);
    int*   bstart = (int*)alloc((size_t)(B + 1) * 4);
    int*   cursor = (int*)alloc((size_t)B * 4);
    int*   rowptr = (int*)alloc((size_t)(N + 1) * 4);
    float* dinv   = (float*)alloc((size_t)N * 4);
    int*   col    = (int*)alloc((size_t)E * 4 + 256);
    size_t shbytes = (size_t)E * 8 > (size_t)N * 64 * 2 ? (size_t)E * 8 : (size_t)N * 64 * 2;
    char*  sh     = alloc(shbytes);
    unsigned short* q = (unsigned short*)alloc((size_t)N * 64 * 2);
    uint2* pairs  = (uint2*)sh;
    unsigned short* g1 = (unsigned short*)sh;   // pairs dead after k_p2
    unsigned short* t  = (unsigned short*)sh;   // g1 dead after agg<true>

    k_zeroB<<<1, 256, 0, stream>>>(bcnt, B);
    k_p1count<<<256, 256, 0, stream>>>(dst, E, B, bcnt);
    k_scanB<<<1, 256, 0, stream>>>(bcnt, B, E, bstart, cursor);
    int nch = (E + P1C - 1) / P1C;
    k_p1place<<<nch, 256, 0, stream>>>(src, dst, E, B, cursor, pairs);
    k_p2<<<B, 512, 0, stream>>>(pairs, bstart, rowptr, dinv, col, N, E);

    int nwaves = (N + 1) / 2;
    int aggblocks = (nwaves + 3) / 4;

    // layer 1: g1 = bf16(dinv*(x@W1)) [MFMA]; q = bf16(dinv*relu(dinv*(sum g1)+b1))
    k_gemm1m<<<(N + 127) / 128, 256, 0, stream>>>(x, W1, dinv, g1, N);
    k_agg<true><<<aggblocks, 256, 0, stream>>>(g1, rowptr, col, dinv, b1, q, N);

    // layer 2 (commuted): t = bf16(dinv*(sum q)); out = log_softmax(t@W2 + b2)
    k_agg<false><<<aggblocks, 256, 0, stream>>>(q, rowptr, col, dinv, b1, t, N);
    k_gemm2s<<<(N + 255) / 256, 256, 0, stream>>>(t, W2, b2, out, N);
}